// Round 8
// baseline (278.464 us; speedup 1.0000x reference)
//
#include <hip/hip_runtime.h>
#include <hip/hip_bf16.h>

// Problem sizes
#define NB 4
#define DIMC 64
#define C2 256
#define HFC 128
#define HH 256
#define WW 256
#define HW (HH * WW)

typedef __attribute__((ext_vector_type(8))) short short8;
typedef __attribute__((ext_vector_type(4))) short s16x4;
typedef __attribute__((ext_vector_type(4))) float f32x4;

__device__ __forceinline__ f32x4 mfma16(short8 a, short8 b, f32x4 c) {
  return __builtin_amdgcn_mfma_f32_16x16x32_bf16(a, b, c, 0, 0, 0);
}

__device__ __forceinline__ short f2bs(float f) {
  __hip_bfloat16 h = __float2bfloat16(f);
  union { __hip_bfloat16 h; short s; } u; u.h = h;
  return u.s;
}

__device__ __forceinline__ float bs2f(short s) {
  union { float f; unsigned u; } v;
  v.u = ((unsigned)(unsigned short)s) << 16;
  return v.f;
}

// Branchless exact-GELU via Abramowitz-Stegun 7.1.26 erf approximation.
__device__ __forceinline__ float fast_gelu(float u) {
  float au = fabsf(u);
  float z = au * 0.70710678118654752f;
  float e = __expf(-z * z);
  float t = __builtin_amdgcn_rcpf(fmaf(0.3275911f, z, 1.0f));
  float p = fmaf(t, 1.061405429f, -1.453152027f);
  p = fmaf(t, p, 1.421413741f);
  p = fmaf(t, p, -0.284496736f);
  p = fmaf(t, p, 0.254829592f);
  p *= t;
  return fmaxf(u, 0.f) - 0.5f * au * p * e;
}

// ---------------------------------------------------------------------------
// prep: per-channel 64x64 spectral matrices from fft_filt (as MFMA A-frags);
// w_in / w_out bf16 A-fragments. Fragment-major: [mblk][kblk][lane][j].
// ---------------------------------------------------------------------------
__global__ __launch_bounds__(64) void prep_kernel(
    const float* __restrict__ w_in, const float* __restrict__ fft,
    const float* __restrict__ w_out, __hip_bfloat16* __restrict__ A1,
    __hip_bfloat16* __restrict__ A2, __hip_bfloat16* __restrict__ Mf) {
  int blk = blockIdx.x;
  int l = threadIdx.x;
  int mm = l & 15, qj = l >> 4;
  if (blk < C2) {
    __shared__ float Feff[64];
    __shared__ float kc[64];
    __shared__ float ct[8];
    if (l < 8) {
      const float s = 0.70710678118654752f;
      const float v0[8] = {1.f, s, 0.f, -s, -1.f, -s, 0.f, s};
      ct[l] = v0[l];
    }
    int c = blk;
    const float* f = fft + c * 40;  // [u][v], v in [0,5)
    int u = l >> 3, v = l & 7;
    int um = (8 - u) & 7;
    float val;
    if (v <= 4) {
      val = f[u * 5 + v];
      if (v == 0 || v == 4) val = 0.5f * (val + f[um * 5 + v]);
    } else {
      val = f[um * 5 + (8 - v)];  // Hermitian extension
    }
    Feff[l] = val;
    __syncthreads();
    int dy = l >> 3, dx = l & 7;
    float s = 0.f;
    for (int uu = 0; uu < 8; ++uu)
      for (int vv = 0; vv < 8; ++vv)
        s += Feff[uu * 8 + vv] * ct[(uu * dy + vv * dx) & 7];
    kc[l] = s * (1.f / 64.f);
    __syncthreads();
    for (int mb = 0; mb < 4; ++mb) {
      int p = mb * 16 + mm;
      int py = p >> 3, px = p & 7;
      for (int kb = 0; kb < 2; ++kb)
        for (int j = 0; j < 8; ++j) {
          int q = kb * 32 + qj * 8 + j;
          int qy = q >> 3, qx = q & 7;
          float kv = kc[((py - qy) & 7) * 8 + ((px - qx) & 7)];
          Mf[(size_t)c * 4096 + (size_t)((mb * 2 + kb) * 64 + l) * 8 + j] =
              __float2bfloat16(kv);
        }
    }
  } else if (blk == C2) {
    for (int mb = 0; mb < 16; ++mb)
      for (int kb = 0; kb < 2; ++kb)
        for (int j = 0; j < 8; ++j) {
          int m = mb * 16 + mm, k = kb * 32 + qj * 8 + j;
          A1[(size_t)((mb * 2 + kb) * 64 + l) * 8 + j] =
              __float2bfloat16(w_in[m * 64 + k]);
        }
  } else {
    for (int mb = 0; mb < 4; ++mb)
      for (int kb = 0; kb < 4; ++kb)
        for (int j = 0; j < 8; ++j) {
          int m = mb * 16 + mm, k = kb * 32 + qj * 8 + j;
          A2[(size_t)((mb * 4 + kb) * 64 + l) * 8 + j] =
              __float2bfloat16(w_out[m * 128 + k]);
        }
  }
}

// ---------------------------------------------------------------------------
// fs_kernel v7: FUSED gemm1 + spectral. R7 analysis: 83 us floor invariant
// across occupancy 8->16 waves/CU and DS vectorization => stalls are GLOBAL
// (barrier-drain convoys + spec_one's serial LDS round-trip). v7:
//   1. hS DOUBLE-BUFFERED -> ONE barrier per chunk (32 -> 16 full drains).
//      Race-free: spec(i) precedes bar(i+1) in program order; gemm1(i+2)
//      (next writer of hS[i&1]) follows bar(i+1) for all waves.
//   2. spec_one stores DIRECTLY to global (4 x b64, 2x128B segments/inst,
//      element-identical addresses to v6's staged epilogue) - removes the
//      LDS stage + lgkmcnt(0) drain + readback from the serial chain.
// All index mappings verbatim from verified v6. 512 threads, 96 KiB LDS.
// ---------------------------------------------------------------------------
#define FS_LDS_BYTES 98304

// hS index (in shorts), relative to a buffer base. row [0,8), patch [0,8),
// qx [0,8). p2 independent of qx -> qx0..qx0+3 contiguous (b64-writable).
__device__ __forceinline__ int hs_idx(int base, int cL, int row, int patch,
                                      int qx) {
  int p2 = (patch ^ cL ^ row) & 7;
  return base + cL * 512 + row * 64 + p2 * 8 + qx;
}

__device__ __forceinline__ void load_mf(short8* dst, const short8* Mfv, int c,
                                        int l) {
#pragma unroll
  for (int f = 0; f < 8; ++f) dst[f] = Mfv[(size_t)c * 512 + f * 64 + l];
}

// spectral for one channel: B from hS[base] (verified v6 mapping), A = mf
// regs, DIRECT b64 global stores (v6-verified addresses, no LDS round-trip).
__device__ __forceinline__ void spec_one(const short* lds, int base,
                                         const short8* mf, int cL, int cg,
                                         int g, int nn16, int l,
                                         __hip_bfloat16* hb, int Py, int x0) {
  int p8 = l & 7;
  short8 bs0 =
      *reinterpret_cast<const short8*>(&lds[hs_idx(base, cL, g, p8, 0)]);
  short8 bs1 =
      *reinterpret_cast<const short8*>(&lds[hs_idx(base, cL, 4 + g, p8, 0)]);
  f32x4 accs[4];
#pragma unroll
  for (int mb = 0; mb < 4; ++mb) {
    accs[mb] = (f32x4){0.f, 0.f, 0.f, 0.f};
    accs[mb] = mfma16(mf[mb * 2 + 0], bs0, accs[mb]);
    accs[mb] = mfma16(mf[mb * 2 + 1], bs1, accs[mb]);
  }
  if (nn16 < 8) {
    // pixel p = mb*16 + g*4 + r: global row = Py*8 + 2mb + (g>>1),
    // global col = x0 + nn16*8 + (g&1)*4 + r  (== v6 staged epilogue)
    __hip_bfloat16* hc = hb + (size_t)cg * HW;
#pragma unroll
    for (int mb = 0; mb < 4; ++mb) {
      s16x4 pk;
#pragma unroll
      for (int r = 0; r < 4; ++r) pk[r] = f2bs(accs[mb][r]);
      __hip_bfloat16* hp = hc +
                           (size_t)(Py * 8 + 2 * mb + (g >> 1)) * WW + x0 +
                           nn16 * 8 + (g & 1) * 4;
      *reinterpret_cast<s16x4*>(hp) = pk;
    }
  }
}

__global__ __launch_bounds__(512, 1) void fs_kernel(
    const float* __restrict__ x, const __hip_bfloat16* __restrict__ A1,
    const __hip_bfloat16* __restrict__ Mf, __hip_bfloat16* __restrict__ h) {
  extern __shared__ char smem[];
  short* lds = reinterpret_cast<short*>(smem);
  int pg = blockIdx.x, b = blockIdx.y;
  int Py = pg >> 2, x0 = (pg & 3) * 64;
  int t = threadIdx.x;
  int w = t >> 6, l = t & 63;  // w in [0,8)
  int g = l >> 4;              // quad
  int nn16 = l & 15;           // MFMA col lane

  const short8* A1v = reinterpret_cast<const short8*>(A1);
  const short8* Mfv = reinterpret_cast<const short8*>(Mf);
  __hip_bfloat16* hb = h + (size_t)b * C2 * HW;

  // issue chunk-0 operand loads FIRST; x staging below hides their latency
  short8 afA0 = A1v[0 * 64 + l];
  short8 afA1 = A1v[1 * 64 + l];
  short8 mfA[8], mfB[8];
  load_mf(mfA, Mfv, w * 2, l);  // chunk 0: wave w's first channel = w*2

  // ---- phase 0: stage x-tile (verified staging; wave w = d-block jb=w) ----
  {
    int n = l;  // pixel [0,64)
    int nblk = n >> 4, nn = n & 15;
    int jb = w;
    int kb = jb >> 2, quad = jb & 3;
#pragma unroll
    for (int py = 0; py < 8; ++py) {
      const float* xb =
          x + (size_t)b * DIMC * HW + (size_t)(Py * 8 + py) * WW + x0 + n;
      short8 pk;
#pragma unroll
      for (int j = 0; j < 8; ++j) pk[j] = f2bs(xb[(size_t)(jb * 8 + j) * HW]);
      *reinterpret_cast<short8*>(
          &lds[(size_t)(py * 512 + (kb * 4 + nblk) * 64 + quad * 16 + nn) * 8]) = pk;
    }
  }

  const short8* xv = reinterpret_cast<const short8*>(lds);

  for (int i = 0; i < 16; ++i) {  // 16 channel-chunks of 16
    int base = 32768 + (i & 1) * 8192;  // double-buffered hS
    __syncthreads();  // (i=0: x-tile ready; i>0: hS[base] consumers done)

    // ---- gemm1 for chunk i, SWAPPED operands; wave w handles row py=w ----
    {
      int py = w;
#pragma unroll
      for (int nb = 0; nb < 4; ++nb) {
        short8 b0 = xv[py * 512 + (0 * 4 + nb) * 64 + l];
        short8 b1 = xv[py * 512 + (1 * 4 + nb) * 64 + l];
        f32x4 acc = (f32x4){0.f, 0.f, 0.f, 0.f};
        acc = mfma16(b0, afA0, acc);  // D[row=pixel][col=channel]
        acc = mfma16(b1, afA1, acc);
        // px = nb*16 + g*4 + r: patch = nb*2 + (g>>1), qx = (g&1)*4 + r
        int patch = nb * 2 + (g >> 1);
        int qx0 = (g & 1) * 4;
        s16x4 pk;
#pragma unroll
        for (int r = 0; r < 4; ++r) pk[r] = f2bs(acc[r]);
        *reinterpret_cast<s16x4*>(&lds[hs_idx(base, nn16, py, patch, qx0)]) = pk;
      }
    }
    // prefetch next chunk's af (consumed after next barrier; i=15 unused)
    int inx = (i + 1) & 15;
    short8 afN0 = A1v[(inx * 2 + 0) * 64 + l];
    short8 afN1 = A1v[(inx * 2 + 1) * 64 + l];
    __syncthreads();  // hS[base] complete for all waves

    // ---- spectral for chunk i: wave w -> channels w*2, w*2+1 ----
    // (no trailing barrier: next chunk's gemm1 writes the OTHER hS buffer;
    //  hS[base] is rewritten only at chunk i+2, after the next barrier)
    int c0 = i * 16 + w * 2;
    load_mf(mfB, Mfv, c0 + 1, l);
    spec_one(lds, base, mfA, w * 2 + 0, c0 + 0, g, nn16, l, hb, Py, x0);
    load_mf(mfA, Mfv, inx * 16 + w * 2, l);  // next chunk's first channel
    spec_one(lds, base, mfB, w * 2 + 1, c0 + 1, g, nn16, l, hb, Py, x0);

    afA0 = afN0;
    afA1 = afN1;
  }
}

// ---------------------------------------------------------------------------
// dwgelu (all batches): depthwise 3x3 (SAME) + gelu-gate, coalesced.
// ---------------------------------------------------------------------------
__global__ __launch_bounds__(256) void dwgelu_kernel(
    const __hip_bfloat16* __restrict__ h2, const float* __restrict__ w_dw,
    __hip_bfloat16* __restrict__ gf) {
  __shared__ short ldsJ[8 * 1024];  // [j][B = r*256 + px], 16 KiB
  int jb = blockIdx.x;     // [0,16)
  int y0 = blockIdx.y * 4; // strip rows y0..y0+3
  int b = blockIdx.z;
  int t = threadIdx.x;
  int j = t >> 5, xg = t & 31;
  int x0 = xg * 8;
  int c1 = jb * 8 + j, c2 = c1 + HFC;
  const __hip_bfloat16* hbase = h2 + (size_t)b * C2 * HW;

  float wd1[9], wd2[9];
#pragma unroll
  for (int k = 0; k < 9; ++k) {
    wd1[k] = w_dw[c1 * 9 + k];
    wd2[k] = w_dw[c2 * 9 + k];
  }

  float acc1[4][8], acc2[4][8];
#pragma unroll
  for (int r = 0; r < 4; ++r)
#pragma unroll
    for (int i = 0; i < 8; ++i) { acc1[r][i] = 0.f; acc2[r][i] = 0.f; }

#pragma unroll
  for (int ir = -1; ir <= 4; ++ir) {
    int yy = y0 + ir;
    bool valid = (yy >= 0) && (yy < HH);
    float f1[10], f2[10];
    if (valid) {
      const __hip_bfloat16* r1 = hbase + ((size_t)c1 * HH + yy) * WW;
      const __hip_bfloat16* r2 = hbase + ((size_t)c2 * HH + yy) * WW;
      short8 v1 = *reinterpret_cast<const short8*>(r1 + x0);
      short8 v2 = *reinterpret_cast<const short8*>(r2 + x0);
#pragma unroll
      for (int i = 0; i < 8; ++i) { f1[i + 1] = bs2f(v1[i]); f2[i + 1] = bs2f(v2[i]); }
      f1[0] = (x0 > 0) ? __bfloat162float(r1[x0 - 1]) : 0.f;
      f2[0] = (x0 > 0) ? __bfloat162float(r2[x0 - 1]) : 0.f;
      f1[9] = (x0 + 8 < WW) ? __bfloat162float(r1[x0 + 8]) : 0.f;
      f2[9] = (x0 + 8 < WW) ? __bfloat162float(r2[x0 + 8]) : 0.f;
    } else {
#pragma unroll
      for (int i = 0; i < 10; ++i) { f1[i] = 0.f; f2[i] = 0.f; }
    }
#pragma unroll
    for (int dy = -1; dy <= 1; ++dy) {
      int r = ir - dy;
      if (r < 0 || r >= 4) continue;
      int ky = dy + 1;
#pragma unroll
      for (int i = 0; i < 8; ++i) {
        acc1[r][i] += f1[i] * wd1[ky * 3] + f1[i + 1] * wd1[ky * 3 + 1] +
                      f1[i + 2] * wd1[ky * 3 + 2];
        acc2[r][i] += f2[i] * wd2[ky * 3] + f2[i + 1] * wd2[ky * 3 + 1] +
                      f2[i + 2] * wd2[ky * 3 + 2];
      }
    }
  }

#pragma unroll
  for (int r = 0; r < 4; ++r) {
    short8 pk;
#pragma unroll
    for (int i = 0; i < 8; ++i) {
      float gg = fast_gelu(acc1[r][i]);
      pk[i] = f2bs(gg * acc2[r][i]);
    }
    *reinterpret_cast<short8*>(&ldsJ[j * 1024 + r * 256 + x0]) = pk;
  }
  __syncthreads();

  int kb = jb >> 2, quad = jb & 3;
  short8* gfv = reinterpret_cast<short8*>(gf) + (size_t)b * 1048576;
#pragma unroll
  for (int k = 0; k < 4; ++k) {
    short8 v;
#pragma unroll
    for (int j2 = 0; j2 < 8; ++j2) v[j2] = ldsJ[j2 * 1024 + k * 256 + t];
    int pix = (y0 + k) * WW + t;
    gfv[((size_t)(pix >> 4) * 4 + kb) * 64 + quad * 16 + (pix & 15)] = v;
  }
}

// ---------------------------------------------------------------------------
// gemm2 (all batches): out[b][o][pix] = sum_hf w_out[o][hf]*g[b][hf][pix].
// ---------------------------------------------------------------------------
__global__ __launch_bounds__(256) void gemm2_kernel(
    const __hip_bfloat16* __restrict__ gf, const __hip_bfloat16* __restrict__ A2,
    float* __restrict__ out) {
  int b = blockIdx.y;
  int pix0 = blockIdx.x * 256;
  int tid = threadIdx.x;
  int w = tid >> 6, l = tid & 63;
  int quad = l >> 4, ln = l & 15;
  const short8* A2v = reinterpret_cast<const short8*>(A2);
  short8 af[4][4];
#pragma unroll
  for (int mb = 0; mb < 4; ++mb)
#pragma unroll
    for (int kb = 0; kb < 4; ++kb) af[mb][kb] = A2v[(mb * 4 + kb) * 64 + l];
  const short8* gv = reinterpret_cast<const short8*>(gf) + (size_t)b * 1048576;
  f32x4 acc[4][4];
#pragma unroll
  for (int i = 0; i < 4; ++i)
#pragma unroll
    for (int j = 0; j < 4; ++j) acc[i][j] = (f32x4){0.f, 0.f, 0.f, 0.f};
#pragma unroll
  for (int nb = 0; nb < 4; ++nb) {
    size_t pixblk = (size_t)blockIdx.x * 16 + w * 4 + nb;
    short8 bf[4];
#pragma unroll
    for (int kb = 0; kb < 4; ++kb) bf[kb] = gv[(pixblk * 4 + kb) * 64 + l];
#pragma unroll
    for (int mb = 0; mb < 4; ++mb)
#pragma unroll
      for (int kb = 0; kb < 4; ++kb)
        acc[mb][nb] = mfma16(af[mb][kb], bf[kb], acc[mb][nb]);
  }
#pragma unroll
  for (int mb = 0; mb < 4; ++mb)
#pragma unroll
    for (int nb = 0; nb < 4; ++nb)
#pragma unroll
      for (int r = 0; r < 4; ++r) {
        int o = mb * 16 + quad * 4 + r;
        int pix = pix0 + w * 64 + nb * 16 + ln;
        out[((size_t)b * DIMC + o) * HW + pix] = acc[mb][nb][r];
      }
}

// ---------------------------------------------------------------------------
// Workspace layout (bytes), ws_size = 256 MiB:
//   0          A1 (w_in frags)     32768
//   32768      A2 (w_out frags)    16384
//   49152      Mf (spectral mats)  2097152
//   2146304    gf (g frags, 4 b)   67108864
//   69255168   h  (bf16, 4 b)      134217728
// ---------------------------------------------------------------------------
extern "C" void kernel_launch(void* const* d_in, const int* in_sizes, int n_in,
                              void* d_out, int out_size, void* d_ws,
                              size_t ws_size, hipStream_t stream) {
  const float* x = (const float*)d_in[0];
  const float* w_in = (const float*)d_in[1];
  const float* w_dw = (const float*)d_in[2];
  const float* fft = (const float*)d_in[3];
  const float* w_out = (const float*)d_in[4];
  float* out = (float*)d_out;
  char* ws = (char*)d_ws;
  __hip_bfloat16* A1 = (__hip_bfloat16*)(ws);
  __hip_bfloat16* A2 = (__hip_bfloat16*)(ws + 32768);
  __hip_bfloat16* Mf = (__hip_bfloat16*)(ws + 49152);
  __hip_bfloat16* gf = (__hip_bfloat16*)(ws + 2146304);
  __hip_bfloat16* h = (__hip_bfloat16*)(ws + 69255168);

  static bool fs_attr_set = false;
  if (!fs_attr_set) {
    (void)hipFuncSetAttribute((const void*)fs_kernel,
                              hipFuncAttributeMaxDynamicSharedMemorySize,
                              FS_LDS_BYTES);
    fs_attr_set = true;
  }

  prep_kernel<<<258, 64, 0, stream>>>(w_in, fft, w_out, A1, A2, Mf);
  fs_kernel<<<dim3(128, NB), 512, FS_LDS_BYTES, stream>>>(x, A1, Mf, h);
  dwgelu_kernel<<<dim3(16, 64, NB), 256, 0, stream>>>(h, w_dw, gf);
  gemm2_kernel<<<dim3(256, NB), 256, 0, stream>>>(gf, A2, out);
}

// Round 9
// 252.702 us; speedup vs baseline: 1.1019x; 1.1019x over previous
//
#include <hip/hip_runtime.h>
#include <hip/hip_bf16.h>

// Problem sizes
#define NB 4
#define DIMC 64
#define C2 256
#define HFC 128
#define HH 256
#define WW 256
#define HW (HH * WW)

typedef __attribute__((ext_vector_type(8))) short short8;
typedef __attribute__((ext_vector_type(4))) short s16x4;
typedef __attribute__((ext_vector_type(4))) float f32x4;

__device__ __forceinline__ f32x4 mfma16(short8 a, short8 b, f32x4 c) {
  return __builtin_amdgcn_mfma_f32_16x16x32_bf16(a, b, c, 0, 0, 0);
}

__device__ __forceinline__ short f2bs(float f) {
  __hip_bfloat16 h = __float2bfloat16(f);
  union { __hip_bfloat16 h; short s; } u; u.h = h;
  return u.s;
}

__device__ __forceinline__ float bs2f(short s) {
  union { float f; unsigned u; } v;
  v.u = ((unsigned)(unsigned short)s) << 16;
  return v.f;
}

// Branchless exact-GELU via Abramowitz-Stegun 7.1.26 erf approximation.
__device__ __forceinline__ float fast_gelu(float u) {
  float au = fabsf(u);
  float z = au * 0.70710678118654752f;
  float e = __expf(-z * z);
  float t = __builtin_amdgcn_rcpf(fmaf(0.3275911f, z, 1.0f));
  float p = fmaf(t, 1.061405429f, -1.453152027f);
  p = fmaf(t, p, 1.421413741f);
  p = fmaf(t, p, -0.284496736f);
  p = fmaf(t, p, 0.254829592f);
  p *= t;
  return fmaxf(u, 0.f) - 0.5f * au * p * e;
}

// ---------------------------------------------------------------------------
// prep: per-channel 64x64 spectral matrices from fft_filt (as MFMA A-frags);
// w_in / w_out bf16 A-fragments. Fragment-major: [mblk][kblk][lane][j].
// ---------------------------------------------------------------------------
__global__ __launch_bounds__(64) void prep_kernel(
    const float* __restrict__ w_in, const float* __restrict__ fft,
    const float* __restrict__ w_out, __hip_bfloat16* __restrict__ A1,
    __hip_bfloat16* __restrict__ A2, __hip_bfloat16* __restrict__ Mf) {
  int blk = blockIdx.x;
  int l = threadIdx.x;
  int mm = l & 15, qj = l >> 4;
  if (blk < C2) {
    __shared__ float Feff[64];
    __shared__ float kc[64];
    __shared__ float ct[8];
    if (l < 8) {
      const float s = 0.70710678118654752f;
      const float v0[8] = {1.f, s, 0.f, -s, -1.f, -s, 0.f, s};
      ct[l] = v0[l];
    }
    int c = blk;
    const float* f = fft + c * 40;  // [u][v], v in [0,5)
    int u = l >> 3, v = l & 7;
    int um = (8 - u) & 7;
    float val;
    if (v <= 4) {
      val = f[u * 5 + v];
      if (v == 0 || v == 4) val = 0.5f * (val + f[um * 5 + v]);
    } else {
      val = f[um * 5 + (8 - v)];  // Hermitian extension
    }
    Feff[l] = val;
    __syncthreads();
    int dy = l >> 3, dx = l & 7;
    float s = 0.f;
    for (int uu = 0; uu < 8; ++uu)
      for (int vv = 0; vv < 8; ++vv)
        s += Feff[uu * 8 + vv] * ct[(uu * dy + vv * dx) & 7];
    kc[l] = s * (1.f / 64.f);
    __syncthreads();
    for (int mb = 0; mb < 4; ++mb) {
      int p = mb * 16 + mm;
      int py = p >> 3, px = p & 7;
      for (int kb = 0; kb < 2; ++kb)
        for (int j = 0; j < 8; ++j) {
          int q = kb * 32 + qj * 8 + j;
          int qy = q >> 3, qx = q & 7;
          float kv = kc[((py - qy) & 7) * 8 + ((px - qx) & 7)];
          Mf[(size_t)c * 4096 + (size_t)((mb * 2 + kb) * 64 + l) * 8 + j] =
              __float2bfloat16(kv);
        }
    }
  } else if (blk == C2) {
    for (int mb = 0; mb < 16; ++mb)
      for (int kb = 0; kb < 2; ++kb)
        for (int j = 0; j < 8; ++j) {
          int m = mb * 16 + mm, k = kb * 32 + qj * 8 + j;
          A1[(size_t)((mb * 2 + kb) * 64 + l) * 8 + j] =
              __float2bfloat16(w_in[m * 64 + k]);
        }
  } else {
    for (int mb = 0; mb < 4; ++mb)
      for (int kb = 0; kb < 4; ++kb)
        for (int j = 0; j < 8; ++j) {
          int m = mb * 16 + mm, k = kb * 32 + qj * 8 + j;
          A2[(size_t)((mb * 4 + kb) * 64 + l) * 8 + j] =
              __float2bfloat16(w_out[m * 128 + k]);
        }
  }
}

// ---------------------------------------------------------------------------
// fs_kernel v6 (REVERTED from v7; R7-verified 81-83 us): FUSED gemm1 +
// spectral, 8 waves/block, 80 KiB LDS, 2 blocks/CU (16 waves/CU).
// ---------------------------------------------------------------------------
#define FS_LDS_BYTES 81920

// hS index (in shorts). row = pixel-row in patch [0,8), patch [0,8), qx [0,8).
// p2 independent of qx -> qx0..qx0+3 contiguous (b64-writable).
__device__ __forceinline__ int hs_idx(int cL, int row, int patch, int qx) {
  int p2 = (patch ^ cL ^ row) & 7;
  return 32768 + cL * 512 + row * 64 + p2 * 8 + qx;
}

__device__ __forceinline__ void load_mf(short8* dst, const short8* Mfv, int c,
                                        int l) {
#pragma unroll
  for (int f = 0; f < 8; ++f) dst[f] = Mfv[(size_t)c * 512 + f * 64 + l];
}

// spectral for one channel: B from hS, A = mf regs, output staged into slot
// cL (wave-private, already consumed) then 1 b128 coalesced global store.
__device__ __forceinline__ void spec_one(short* lds, const short8* mf, int cL,
                                         int cg, int g, int nn16, int l,
                                         __hip_bfloat16* hb, int Py, int x0) {
  int p8 = l & 7;
  short8 bs0 = *reinterpret_cast<const short8*>(&lds[hs_idx(cL, g, p8, 0)]);
  short8 bs1 = *reinterpret_cast<const short8*>(&lds[hs_idx(cL, 4 + g, p8, 0)]);
  f32x4 accs[4];
#pragma unroll
  for (int mb = 0; mb < 4; ++mb) {
    accs[mb] = (f32x4){0.f, 0.f, 0.f, 0.f};
    accs[mb] = mfma16(mf[mb * 2 + 0], bs0, accs[mb]);
    accs[mb] = mfma16(mf[mb * 2 + 1], bs1, accs[mb]);
  }
  int slot = 32768 + cL * 512;
  if (nn16 < 8) {
    // pixels p = mb*16 + g*4 + r: (p>>3) = 2mb + (g>>1), (p&7) = (g&1)*4 + r
    int prow2 = g >> 1, pcol0 = (g & 1) * 4;
#pragma unroll
    for (int mb = 0; mb < 4; ++mb) {
      s16x4 pk;
#pragma unroll
      for (int r = 0; r < 4; ++r) pk[r] = f2bs(accs[mb][r]);
      *reinterpret_cast<s16x4*>(
          &lds[slot + (2 * mb + prow2) * 64 + nn16 * 8 + pcol0]) = pk;
    }
  }
  asm volatile("s_waitcnt lgkmcnt(0)" ::: "memory");
  short8 ov = *reinterpret_cast<const short8*>(&lds[slot + l * 8]);
  __hip_bfloat16* hp = hb + (size_t)cg * HW +
                       (size_t)(Py * 8 + (l >> 3)) * WW + x0 + (l & 7) * 8;
  *reinterpret_cast<short8*>(hp) = ov;
}

__global__ __launch_bounds__(512, 4) void fs_kernel(
    const float* __restrict__ x, const __hip_bfloat16* __restrict__ A1,
    const __hip_bfloat16* __restrict__ Mf, __hip_bfloat16* __restrict__ h) {
  extern __shared__ char smem[];
  short* lds = reinterpret_cast<short*>(smem);
  int pg = blockIdx.x, b = blockIdx.y;
  int Py = pg >> 2, x0 = (pg & 3) * 64;
  int t = threadIdx.x;
  int w = t >> 6, l = t & 63;  // w in [0,8)
  int g = l >> 4;              // quad
  int nn16 = l & 15;           // MFMA col lane

  const short8* A1v = reinterpret_cast<const short8*>(A1);
  const short8* Mfv = reinterpret_cast<const short8*>(Mf);
  __hip_bfloat16* hb = h + (size_t)b * C2 * HW;

  // issue chunk-0 operand loads FIRST; x staging below hides their latency
  short8 afA0 = A1v[0 * 64 + l];
  short8 afA1 = A1v[1 * 64 + l];
  short8 mfA[8], mfB[8];
  load_mf(mfA, Mfv, w * 2, l);  // chunk 0: wave w's first channel = w*2

  // ---- phase 0: stage x-tile (verified staging; wave w = d-block jb=w) ----
  {
    int n = l;  // pixel [0,64)
    int nblk = n >> 4, nn = n & 15;
    int jb = w;
    int kb = jb >> 2, quad = jb & 3;
#pragma unroll
    for (int py = 0; py < 8; ++py) {
      const float* xb =
          x + (size_t)b * DIMC * HW + (size_t)(Py * 8 + py) * WW + x0 + n;
      short8 pk;
#pragma unroll
      for (int j = 0; j < 8; ++j) pk[j] = f2bs(xb[(size_t)(jb * 8 + j) * HW]);
      *reinterpret_cast<short8*>(
          &lds[(size_t)(py * 512 + (kb * 4 + nblk) * 64 + quad * 16 + nn) * 8]) = pk;
    }
  }
  __syncthreads();

  const short8* xv = reinterpret_cast<const short8*>(lds);

  for (int i = 0; i < 16; ++i) {  // 16 channel-chunks of 16
    // ---- gemm1 for chunk i, SWAPPED operands; wave w handles row py=w ----
    {
      int py = w;
#pragma unroll
      for (int nb = 0; nb < 4; ++nb) {
        short8 b0 = xv[py * 512 + (0 * 4 + nb) * 64 + l];
        short8 b1 = xv[py * 512 + (1 * 4 + nb) * 64 + l];
        f32x4 acc = (f32x4){0.f, 0.f, 0.f, 0.f};
        acc = mfma16(b0, afA0, acc);  // D[row=pixel][col=channel]
        acc = mfma16(b1, afA1, acc);
        // px = nb*16 + g*4 + r: patch = nb*2 + (g>>1), qx = (g&1)*4 + r
        int patch = nb * 2 + (g >> 1);
        int qx0 = (g & 1) * 4;
        s16x4 pk;
#pragma unroll
        for (int r = 0; r < 4; ++r) pk[r] = f2bs(acc[r]);
        *reinterpret_cast<s16x4*>(&lds[hs_idx(nn16, py, patch, qx0)]) = pk;
      }
    }
    // prefetch next chunk's af (consumed 2 barriers later; i=15 wraps, unused)
    int inx = (i + 1) & 15;
    short8 afN0 = A1v[(inx * 2 + 0) * 64 + l];
    short8 afN1 = A1v[(inx * 2 + 1) * 64 + l];
    __syncthreads();

    // ---- spectral for chunk i: wave w -> channels w*2, w*2+1 ----
    int c0 = i * 16 + w * 2;
    load_mf(mfB, Mfv, c0 + 1, l);
    spec_one(lds, mfA, w * 2 + 0, c0 + 0, g, nn16, l, hb, Py, x0);
    load_mf(mfA, Mfv, inx * 16 + w * 2, l);  // next chunk's first channel
    spec_one(lds, mfB, w * 2 + 1, c0 + 1, g, nn16, l, hb, Py, x0);
    __syncthreads();  // hS consumed before next chunk's gemm1 overwrites

    afA0 = afN0;
    afA1 = afN1;
  }
}

// ---------------------------------------------------------------------------
// dwgelu v5 (all batches): depthwise 3x3 (SAME) + gelu-gate, coalesced.
// R9: 8-row strips (was 4). Per-output-row loads 1.5 -> 1.25; 2x per-thread
// ILP; blocks halve. ROLLING FINALIZE: row r completes after ir = r+1, so
// gate+pack+LDS-write happens inside the ir loop -> live acc <= ~3 rows
// (keeps VGPR bounded). Gather/store = verified mapping with k=0..7.
// ---------------------------------------------------------------------------
__global__ __launch_bounds__(256) void dwgelu_kernel(
    const __hip_bfloat16* __restrict__ h2, const float* __restrict__ w_dw,
    __hip_bfloat16* __restrict__ gf) {
  __shared__ short ldsJ[8 * 2048];  // [j][k*256 + px], 32 KiB
  int jb = blockIdx.x;     // [0,16)
  int y0 = blockIdx.y * 8; // strip rows y0..y0+7
  int b = blockIdx.z;
  int t = threadIdx.x;
  int j = t >> 5, xg = t & 31;
  int x0 = xg * 8;
  int c1 = jb * 8 + j, c2 = c1 + HFC;
  const __hip_bfloat16* hbase = h2 + (size_t)b * C2 * HW;

  float wd1[9], wd2[9];
#pragma unroll
  for (int k = 0; k < 9; ++k) {
    wd1[k] = w_dw[c1 * 9 + k];
    wd2[k] = w_dw[c2 * 9 + k];
  }

  float acc1[8][8], acc2[8][8];
#pragma unroll
  for (int r = 0; r < 8; ++r)
#pragma unroll
    for (int i = 0; i < 8; ++i) { acc1[r][i] = 0.f; acc2[r][i] = 0.f; }

#pragma unroll
  for (int ir = -1; ir <= 8; ++ir) {
    int yy = y0 + ir;
    bool valid = (yy >= 0) && (yy < HH);
    float f1[10], f2[10];
    if (valid) {
      const __hip_bfloat16* r1 = hbase + ((size_t)c1 * HH + yy) * WW;
      const __hip_bfloat16* r2 = hbase + ((size_t)c2 * HH + yy) * WW;
      short8 v1 = *reinterpret_cast<const short8*>(r1 + x0);
      short8 v2 = *reinterpret_cast<const short8*>(r2 + x0);
#pragma unroll
      for (int i = 0; i < 8; ++i) { f1[i + 1] = bs2f(v1[i]); f2[i + 1] = bs2f(v2[i]); }
      f1[0] = (x0 > 0) ? __bfloat162float(r1[x0 - 1]) : 0.f;
      f2[0] = (x0 > 0) ? __bfloat162float(r2[x0 - 1]) : 0.f;
      f1[9] = (x0 + 8 < WW) ? __bfloat162float(r1[x0 + 8]) : 0.f;
      f2[9] = (x0 + 8 < WW) ? __bfloat162float(r2[x0 + 8]) : 0.f;
    } else {
#pragma unroll
      for (int i = 0; i < 10; ++i) { f1[i] = 0.f; f2[i] = 0.f; }
    }
#pragma unroll
    for (int dy = -1; dy <= 1; ++dy) {
      int r = ir - dy;
      if (r < 0 || r >= 8) continue;
      int ky = dy + 1;
#pragma unroll
      for (int i = 0; i < 8; ++i) {
        acc1[r][i] += f1[i] * wd1[ky * 3] + f1[i + 1] * wd1[ky * 3 + 1] +
                      f1[i + 2] * wd1[ky * 3 + 2];
        acc2[r][i] += f2[i] * wd2[ky * 3] + f2[i + 1] * wd2[ky * 3 + 1] +
                      f2[i + 2] * wd2[ky * 3 + 2];
      }
    }
    // rolling finalize: row (ir-1) has received all 3 dy-contributions
    if (ir >= 1) {
      int r = ir - 1;
      short8 pk;
#pragma unroll
      for (int i = 0; i < 8; ++i) {
        float gg = fast_gelu(acc1[r][i]);
        pk[i] = f2bs(gg * acc2[r][i]);
      }
      *reinterpret_cast<short8*>(&ldsJ[j * 2048 + r * 256 + x0]) = pk;
    }
  }
  __syncthreads();

  int kb = jb >> 2, quad = jb & 3;
  short8* gfv = reinterpret_cast<short8*>(gf) + (size_t)b * 1048576;
#pragma unroll
  for (int k = 0; k < 8; ++k) {
    short8 v;
#pragma unroll
    for (int j2 = 0; j2 < 8; ++j2) v[j2] = ldsJ[j2 * 2048 + k * 256 + t];
    int pix = (y0 + k) * WW + t;
    gfv[((size_t)(pix >> 4) * 4 + kb) * 64 + quad * 16 + (pix & 15)] = v;
  }
}

// ---------------------------------------------------------------------------
// gemm2 (all batches): out[b][o][pix] = sum_hf w_out[o][hf]*g[b][hf][pix].
// ---------------------------------------------------------------------------
__global__ __launch_bounds__(256) void gemm2_kernel(
    const __hip_bfloat16* __restrict__ gf, const __hip_bfloat16* __restrict__ A2,
    float* __restrict__ out) {
  int b = blockIdx.y;
  int pix0 = blockIdx.x * 256;
  int tid = threadIdx.x;
  int w = tid >> 6, l = tid & 63;
  int quad = l >> 4, ln = l & 15;
  const short8* A2v = reinterpret_cast<const short8*>(A2);
  short8 af[4][4];
#pragma unroll
  for (int mb = 0; mb < 4; ++mb)
#pragma unroll
    for (int kb = 0; kb < 4; ++kb) af[mb][kb] = A2v[(mb * 4 + kb) * 64 + l];
  const short8* gv = reinterpret_cast<const short8*>(gf) + (size_t)b * 1048576;
  f32x4 acc[4][4];
#pragma unroll
  for (int i = 0; i < 4; ++i)
#pragma unroll
    for (int j = 0; j < 4; ++j) acc[i][j] = (f32x4){0.f, 0.f, 0.f, 0.f};
#pragma unroll
  for (int nb = 0; nb < 4; ++nb) {
    size_t pixblk = (size_t)blockIdx.x * 16 + w * 4 + nb;
    short8 bf[4];
#pragma unroll
    for (int kb = 0; kb < 4; ++kb) bf[kb] = gv[(pixblk * 4 + kb) * 64 + l];
#pragma unroll
    for (int mb = 0; mb < 4; ++mb)
#pragma unroll
      for (int kb = 0; kb < 4; ++kb)
        acc[mb][nb] = mfma16(af[mb][kb], bf[kb], acc[mb][nb]);
  }
#pragma unroll
  for (int mb = 0; mb < 4; ++mb)
#pragma unroll
    for (int nb = 0; nb < 4; ++nb)
#pragma unroll
      for (int r = 0; r < 4; ++r) {
        int o = mb * 16 + quad * 4 + r;
        int pix = pix0 + w * 64 + nb * 16 + ln;
        out[((size_t)b * DIMC + o) * HW + pix] = acc[mb][nb][r];
      }
}

// ---------------------------------------------------------------------------
// Workspace layout (bytes), ws_size = 256 MiB:
//   0          A1 (w_in frags)     32768
//   32768      A2 (w_out frags)    16384
//   49152      Mf (spectral mats)  2097152
//   2146304    gf (g frags, 4 b)   67108864
//   69255168   h  (bf16, 4 b)      134217728
// ---------------------------------------------------------------------------
extern "C" void kernel_launch(void* const* d_in, const int* in_sizes, int n_in,
                              void* d_out, int out_size, void* d_ws,
                              size_t ws_size, hipStream_t stream) {
  const float* x = (const float*)d_in[0];
  const float* w_in = (const float*)d_in[1];
  const float* w_dw = (const float*)d_in[2];
  const float* fft = (const float*)d_in[3];
  const float* w_out = (const float*)d_in[4];
  float* out = (float*)d_out;
  char* ws = (char*)d_ws;
  __hip_bfloat16* A1 = (__hip_bfloat16*)(ws);
  __hip_bfloat16* A2 = (__hip_bfloat16*)(ws + 32768);
  __hip_bfloat16* Mf = (__hip_bfloat16*)(ws + 49152);
  __hip_bfloat16* gf = (__hip_bfloat16*)(ws + 2146304);
  __hip_bfloat16* h = (__hip_bfloat16*)(ws + 69255168);

  static bool fs_attr_set = false;
  if (!fs_attr_set) {
    (void)hipFuncSetAttribute((const void*)fs_kernel,
                              hipFuncAttributeMaxDynamicSharedMemorySize,
                              FS_LDS_BYTES);
    fs_attr_set = true;
  }

  prep_kernel<<<258, 64, 0, stream>>>(w_in, fft, w_out, A1, A2, Mf);
  fs_kernel<<<dim3(128, NB), 512, FS_LDS_BYTES, stream>>>(x, A1, Mf, h);
  dwgelu_kernel<<<dim3(16, 32, NB), 256, 0, stream>>>(h, w_dw, gf);
  gemm2_kernel<<<dim3(256, NB), 256, 0, stream>>>(gf, A2, out);
}